// Round 14
// baseline (22.084 us; speedup 1.0000x reference)
//
#include <hip/hip_runtime.h>
#include <hip/hip_bf16.h>
#include <math.h>

// R13: R11's best kernel (14.86us), with k2 replaced by a 4-byte memset node
// + one device-scope atomicAdd(out) per block (order noise ~1e-6 << 2.2e-2,
// pattern validated R3'/R4).
// k1: block = (batch, 64-pred panel), grid 512 (2 blocks/CU, 64KB LDS).
//     All 2048 targets packed in LDS once per block; the 4 waves each own a
//     512-target QUARTER and both 32-pred tiles (2 independent MFMAs/iter).
//     Full min over all targets completes IN-BLOCK (LDS quarter-merge), then
//     epilogue (d^2/2 -> dist, asym, blend) and ONE atomicAdd per block.
// MFMA packing (R7/R8/R10/R11-validated, absmax ~0):
//   A row r (target): k0-2=th, k3-5=th, k6-8=tl | k9=qh, k10=ql
//   B col c (pred)  : k0-2=-ph, k3-5=-pl, k6-8=-ph | k9=1, k10=1
//   dot = 0.5*t^2 - p.t;  d^2/2 = dot + 0.5*p^2 (added in epilogue).

typedef short short8 __attribute__((ext_vector_type(8)));
typedef float f32x16 __attribute__((ext_vector_type(16)));

__device__ __forceinline__ unsigned short f2bf(float f) {  // RNE f32->bf16
  unsigned u = __float_as_uint(f);
  u = u + 0x7FFFu + ((u >> 16) & 1u);
  return (unsigned short)(u >> 16);
}
__device__ __forceinline__ float bf2f(unsigned short h) {
  return __uint_as_float(((unsigned)h) << 16);
}

#define TPB 256
#define NPTS 2048

__global__ __launch_bounds__(TPB, 2) void chamfer_main_kernel(
    const float* __restrict__ pred, const float* __restrict__ targ,
    const float* __restrict__ sym_flag, float* __restrict__ out,
    int N, int B, int panelsPerBatch, float invNB) {
  __shared__ short8 sA[2][NPTS];  // 64 KB packed A fragments (both K-halves)
  __shared__ float sm[4][64];     // per-quarter col mins

  const int blk = blockIdx.x;
  const int pp = blk % panelsPerBatch;  // 64-pred panel (32 per batch)
  const int b = blk / panelsPerBatch;

  // ---- stage + pack ALL targets of this batch (8 per thread)
  const float* tb = targ + (size_t)b * N * 3;
  for (int t = threadIdx.x; t < NPTS; t += TPB) {
    const float x = tb[t * 3], y = tb[t * 3 + 1], z = tb[t * 3 + 2];
    const unsigned short thx = f2bf(x), thy = f2bf(y), thz = f2bf(z);
    const unsigned short tlx = f2bf(x - bf2f(thx));
    const unsigned short tly = f2bf(y - bf2f(thy));
    const unsigned short tlz = f2bf(z - bf2f(thz));
    const float q = 0.5f * (x * x + y * y + z * z);
    const unsigned short qh = f2bf(q), ql = f2bf(q - bf2f(qh));
    sA[0][t] = short8{(short)thx, (short)thy, (short)thz, (short)thx,
                      (short)thy, (short)thz, (short)tlx, (short)tly};
    sA[1][t] = short8{(short)tlz, (short)qh, (short)ql, 0, 0, 0, 0, 0};
  }

  const int lane = threadIdx.x & 63;
  const int w = threadIdx.x >> 6;  // wave = target quarter 0..3
  const int g = lane >> 5;         // K-half this lane supplies
  const int l31 = lane & 31;
  const int colBase = pp * 64;

  // ---- B fragments for BOTH 32-pred tiles of the panel (negated hi/lo)
  short8 bf0, bf1;
#pragma unroll
  for (int pt = 0; pt < 2; ++pt) {
    const int col = colBase + pt * 32 + l31;
    const float* pq = pred + ((size_t)b * N + col) * 3;
    const float x = pq[0], y = pq[1], z = pq[2];
    const unsigned short hx = f2bf(-x), hy = f2bf(-y), hz = f2bf(-z);
    const unsigned short lx = f2bf(-x - bf2f(hx));
    const unsigned short ly = f2bf(-y - bf2f(hy));
    const unsigned short lz = f2bf(-z - bf2f(hz));
    short8 r;
    if (g == 0)
      r = short8{(short)hx, (short)hy, (short)hz, (short)lx,
                 (short)ly, (short)lz, (short)hx, (short)hy};
    else
      r = short8{(short)hz, (short)0x3F80, (short)0x3F80, 0, 0, 0, 0, 0};
    if (pt == 0) bf0 = r; else bf1 = r;
  }
  __syncthreads();

  const f32x16 zc = {0.f, 0.f, 0.f, 0.f, 0.f, 0.f, 0.f, 0.f,
                     0.f, 0.f, 0.f, 0.f, 0.f, 0.f, 0.f, 0.f};
  float rm0[8], rm1[8];
#pragma unroll
  for (int i = 0; i < 8; ++i) { rm0[i] = 3.4e38f; rm1[i] = 3.4e38f; }

  // ---- this wave's 512-target quarter: 16 x (1 ds_read + 2 indep MFMA)
#pragma unroll 4
  for (int ta = 0; ta < 16; ++ta) {
    const short8 a = sA[g][w * 512 + ta * 32 + l31];
    const f32x16 d0 = __builtin_amdgcn_mfma_f32_32x32x16_bf16(a, bf0, zc, 0, 0, 0);
    const f32x16 d1 = __builtin_amdgcn_mfma_f32_32x32x16_bf16(a, bf1, zc, 0, 0, 0);
#pragma unroll
    for (int i = 0; i < 8; ++i) {
      rm0[i] = fminf(rm0[i], fminf(d0[2 * i], d0[2 * i + 1]));  // v_min3
      rm1[i] = fminf(rm1[i], fminf(d1[2 * i], d1[2 * i + 1]));
    }
  }

  // ---- per-col min for this quarter -> LDS
  float m0 = rm0[0], m1 = rm1[0];
#pragma unroll
  for (int i = 1; i < 8; ++i) { m0 = fminf(m0, rm0[i]); m1 = fminf(m1, rm1[i]); }
  m0 = fminf(m0, __shfl_xor(m0, 32));  // merge K-half rows (lane^32)
  m1 = fminf(m1, __shfl_xor(m1, 32));
  if (lane < 32) {
    sm[w][l31] = m0;
    sm[w][32 + l31] = m1;
  }
  __syncthreads();  // quarter merge

  // ---- epilogue: threads 0..63 (wave 0) own the panel's 64 preds
  if (threadIdx.x < 64) {
    const int i = threadIdx.x;
    const float mm = fminf(fminf(sm[0][i], sm[1][i]), fminf(sm[2][i], sm[3][i]));
    const size_t gc = (size_t)b * N + colBase + i;
    const float x = pred[gc * 3], y = pred[gc * 3 + 1], z = pred[gc * 3 + 2];
    const float tx = targ[gc * 3], ty = targ[gc * 3 + 1], tz = targ[gc * 3 + 2];
    const float hp2 = 0.5f * (x * x + y * y + z * z);
    const float dsym = sqrtf(fmaxf(2.f * (mm + hp2), 1e-12f));
    const float dx = x - tx, dy = y - ty, dz = z - tz;
    const float dasym = sqrtf(dx * dx + dy * dy + dz * dz);
    const float f = sym_flag[b];
    float c = f * dsym + (1.f - f) * dasym;
#pragma unroll
    for (int off = 32; off > 0; off >>= 1) c += __shfl_xor(c, off);
    if (i == 0) atomicAdd(out, c * invNB);  // device-scope, one per block
  }
}

extern "C" void kernel_launch(void* const* d_in, const int* in_sizes, int n_in,
                              void* d_out, int out_size, void* d_ws, size_t ws_size,
                              hipStream_t stream) {
  const float* pred = (const float*)d_in[0];
  const float* targ = (const float*)d_in[1];
  const float* sym_flag = (const float*)d_in[2];
  float* out = (float*)d_out;

  const int B = in_sizes[2];            // 16
  const int N = in_sizes[0] / (B * 3);  // 2048 (kernel sized for this)

  const int panelsPerBatch = N / 64;    // 32
  const int grid = B * panelsPerBatch;  // 512

  hipMemsetAsync(out, 0, sizeof(float), stream);  // cheapest possible node
  chamfer_main_kernel<<<grid, TPB, 0, stream>>>(
      pred, targ, sym_flag, out, N, B, panelsPerBatch, 1.0f / (float)(N * B));
}

// Round 15
// 14.263 us; speedup vs baseline: 1.5483x; 1.5483x over previous
//
#include <hip/hip_runtime.h>
#include <hip/hip_bf16.h>
#include <math.h>

// R14: R11's winning structure with pack redundancy halved.
// k1: block = (batch, 128-pred panel), TPB=512 (8 waves), grid 256 = 1/CU
//     (2 waves/SIMD, same occupancy as R11's 2x256). All 2048 targets packed
//     once per block (4 per thread, half of R11's 8). Wave (q=w&3, h=w>>2)
//     computes target-quarter q x pred-half h: 16 x (1 ds_read + 2 indep
//     MFMA + 16 min3). Quarter-merge via sm[4][128]; epilogue threads 0..127;
//     ONE plain f32 partial per block (NO atomics - R13 lesson: 512 same-
//     address device atomics cost ~7us).
// k2: one block sums 256 partials in fixed order -> out[0].
// MFMA packing (R7/R8/R10/R11-validated, absmax ~0):
//   A row r (target): k0-2=th, k3-5=th, k6-8=tl | k9=qh, k10=ql
//   B col c (pred)  : k0-2=-ph, k3-5=-pl, k6-8=-ph | k9=1, k10=1
//   dot = 0.5*t^2 - p.t;  d^2/2 = dot + 0.5*p^2 (added in epilogue).

typedef short short8 __attribute__((ext_vector_type(8)));
typedef float f32x16 __attribute__((ext_vector_type(16)));

__device__ __forceinline__ unsigned short f2bf(float f) {  // RNE f32->bf16
  unsigned u = __float_as_uint(f);
  u = u + 0x7FFFu + ((u >> 16) & 1u);
  return (unsigned short)(u >> 16);
}
__device__ __forceinline__ float bf2f(unsigned short h) {
  return __uint_as_float(((unsigned)h) << 16);
}

#define TPB 512
#define NPTS 2048

__global__ __launch_bounds__(TPB, 1) void chamfer_main_kernel(
    const float* __restrict__ pred, const float* __restrict__ targ,
    const float* __restrict__ sym_flag, float* __restrict__ partial,
    int N, int B, int panelsPerBatch) {
  __shared__ short8 sA[2][NPTS];  // 64 KB packed A fragments (both K-halves)
  __shared__ float sm[4][128];    // per-quarter col mins (2-way alias: free)
  __shared__ float sW[2];

  const int blk = blockIdx.x;
  const int pp = blk % panelsPerBatch;  // 128-pred panel (16 per batch)
  const int b = blk / panelsPerBatch;

  // ---- stage + pack ALL targets of this batch (4 per thread)
  const float* tb = targ + (size_t)b * N * 3;
  for (int t = threadIdx.x; t < NPTS; t += TPB) {
    const float x = tb[t * 3], y = tb[t * 3 + 1], z = tb[t * 3 + 2];
    const unsigned short thx = f2bf(x), thy = f2bf(y), thz = f2bf(z);
    const unsigned short tlx = f2bf(x - bf2f(thx));
    const unsigned short tly = f2bf(y - bf2f(thy));
    const unsigned short tlz = f2bf(z - bf2f(thz));
    const float q = 0.5f * (x * x + y * y + z * z);
    const unsigned short qh = f2bf(q), ql = f2bf(q - bf2f(qh));
    sA[0][t] = short8{(short)thx, (short)thy, (short)thz, (short)thx,
                      (short)thy, (short)thz, (short)tlx, (short)tly};
    sA[1][t] = short8{(short)tlz, (short)qh, (short)ql, 0, 0, 0, 0, 0};
  }

  const int lane = threadIdx.x & 63;
  const int w = threadIdx.x >> 6;  // wave 0..7
  const int q = w & 3;             // target quarter
  const int h = w >> 2;            // pred half (0..1)
  const int g = lane >> 5;         // K-half this lane supplies
  const int l31 = lane & 31;
  const int colBase = pp * 128 + h * 64;  // this wave's 64-pred range

  // ---- B fragments for this wave's two 32-pred tiles (negated hi/lo)
  short8 bf0, bf1;
#pragma unroll
  for (int pt = 0; pt < 2; ++pt) {
    const int col = colBase + pt * 32 + l31;
    const float* pq = pred + ((size_t)b * N + col) * 3;
    const float x = pq[0], y = pq[1], z = pq[2];
    const unsigned short hx = f2bf(-x), hy = f2bf(-y), hz = f2bf(-z);
    const unsigned short lx = f2bf(-x - bf2f(hx));
    const unsigned short ly = f2bf(-y - bf2f(hy));
    const unsigned short lz = f2bf(-z - bf2f(hz));
    short8 r;
    if (g == 0)
      r = short8{(short)hx, (short)hy, (short)hz, (short)lx,
                 (short)ly, (short)lz, (short)hx, (short)hy};
    else
      r = short8{(short)hz, (short)0x3F80, (short)0x3F80, 0, 0, 0, 0, 0};
    if (pt == 0) bf0 = r; else bf1 = r;
  }
  __syncthreads();

  const f32x16 zc = {0.f, 0.f, 0.f, 0.f, 0.f, 0.f, 0.f, 0.f,
                     0.f, 0.f, 0.f, 0.f, 0.f, 0.f, 0.f, 0.f};
  float rm0[8], rm1[8];
#pragma unroll
  for (int i = 0; i < 8; ++i) { rm0[i] = 3.4e38f; rm1[i] = 3.4e38f; }

  // ---- this wave's 512-target quarter: 16 x (1 ds_read + 2 indep MFMA)
#pragma unroll 4
  for (int ta = 0; ta < 16; ++ta) {
    const short8 a = sA[g][q * 512 + ta * 32 + l31];
    const f32x16 d0 = __builtin_amdgcn_mfma_f32_32x32x16_bf16(a, bf0, zc, 0, 0, 0);
    const f32x16 d1 = __builtin_amdgcn_mfma_f32_32x32x16_bf16(a, bf1, zc, 0, 0, 0);
#pragma unroll
    for (int i = 0; i < 8; ++i) {
      rm0[i] = fminf(rm0[i], fminf(d0[2 * i], d0[2 * i + 1]));  // v_min3
      rm1[i] = fminf(rm1[i], fminf(d1[2 * i], d1[2 * i + 1]));
    }
  }

  // ---- per-col min for this quarter -> LDS
  float m0 = rm0[0], m1 = rm1[0];
#pragma unroll
  for (int i = 1; i < 8; ++i) { m0 = fminf(m0, rm0[i]); m1 = fminf(m1, rm1[i]); }
  m0 = fminf(m0, __shfl_xor(m0, 32));  // merge K-half rows (lane^32)
  m1 = fminf(m1, __shfl_xor(m1, 32));
  if (lane < 32) {
    sm[q][h * 64 + l31] = m0;
    sm[q][h * 64 + 32 + l31] = m1;
  }
  __syncthreads();  // quarter merge

  // ---- epilogue: threads 0..127 own the panel's 128 preds
  if (threadIdx.x < 128) {
    const int i = threadIdx.x;
    const float mm = fminf(fminf(sm[0][i], sm[1][i]), fminf(sm[2][i], sm[3][i]));
    const size_t gc = (size_t)b * N + pp * 128 + i;
    const float x = pred[gc * 3], y = pred[gc * 3 + 1], z = pred[gc * 3 + 2];
    const float tx = targ[gc * 3], ty = targ[gc * 3 + 1], tz = targ[gc * 3 + 2];
    const float hp2 = 0.5f * (x * x + y * y + z * z);
    const float dsym = sqrtf(fmaxf(2.f * (mm + hp2), 1e-12f));
    const float dx = x - tx, dy = y - ty, dz = z - tz;
    const float dasym = sqrtf(dx * dx + dy * dy + dz * dz);
    const float f = sym_flag[b];
    float c = f * dsym + (1.f - f) * dasym;
#pragma unroll
    for (int off = 32; off > 0; off >>= 1) c += __shfl_xor(c, off);
    if (lane == 0) sW[threadIdx.x >> 6] = c;
  }
  __syncthreads();
  if (threadIdx.x == 0) partial[blk] = sW[0] + sW[1];  // plain store
}

// k2: one block, fixed-order sum of 256 partials.
__global__ __launch_bounds__(256) void chamfer_sum_kernel(
    const float* __restrict__ partial, float* __restrict__ out, float invNB) {
  const int t = threadIdx.x;
  float s = partial[t];
#pragma unroll
  for (int off = 32; off > 0; off >>= 1) s += __shfl_xor(s, off);
  __shared__ float sW[4];
  if ((t & 63) == 0) sW[t >> 6] = s;
  __syncthreads();
  if (t == 0) out[0] = (sW[0] + sW[1] + sW[2] + sW[3]) * invNB;
}

extern "C" void kernel_launch(void* const* d_in, const int* in_sizes, int n_in,
                              void* d_out, int out_size, void* d_ws, size_t ws_size,
                              hipStream_t stream) {
  const float* pred = (const float*)d_in[0];
  const float* targ = (const float*)d_in[1];
  const float* sym_flag = (const float*)d_in[2];
  float* out = (float*)d_out;

  const int B = in_sizes[2];            // 16
  const int N = in_sizes[0] / (B * 3);  // 2048 (kernels sized for this)

  const int panelsPerBatch = N / 128;   // 16
  const int grid = B * panelsPerBatch;  // 256 = 1 block/CU
  float* partial = (float*)d_ws;        // 256 floats

  chamfer_main_kernel<<<grid, TPB, 0, stream>>>(pred, targ, sym_flag, partial,
                                                N, B, panelsPerBatch);
  chamfer_sum_kernel<<<1, 256, 0, stream>>>(partial, out,
                                            1.0f / (float)(N * B));
}